// Round 3
// baseline (843.892 us; speedup 1.0000x reference)
//
#include <hip/hip_runtime.h>

#define N_SEGMENTS 50000
#define N_ROWS     1600000
#define N_FEAT     64

// ---------- Phase A: histogram of segment ids (int4-vectorized) ----------
__global__ void hist_kernel(const int* __restrict__ idx, int* __restrict__ counts) {
    int i = (blockIdx.x * 256 + threadIdx.x) * 4;
    if (i + 3 < N_ROWS) {
        int4 v = *(const int4*)(idx + i);
        atomicAdd(&counts[v.x], 1);
        atomicAdd(&counts[v.y], 1);
        atomicAdd(&counts[v.z], 1);
        atomicAdd(&counts[v.w], 1);
    } else {
        for (int k = i; k < N_ROWS; ++k) atomicAdd(&counts[idx[k]], 1);
    }
}

// ---------- Phase B: exclusive scan, single block, 2-pass register scan ----
// 1024 threads x CHUNK=49 contiguous elements each (1024*49 = 50176 >= 50001).
#define SCAN_CHUNK 49

__device__ __forceinline__ int wave_incl_scan(int v) {
    int lane = threadIdx.x & 63;
#pragma unroll
    for (int d = 1; d < 64; d <<= 1) {
        int t = __shfl_up(v, d, 64);
        if (lane >= d) v += t;
    }
    return v;
}

__global__ void __launch_bounds__(1024)
scan_kernel(const int* __restrict__ counts,
            int* __restrict__ seg_start,
            int* __restrict__ cursor) {
    __shared__ int wave_sums[16];
    const int tid  = threadIdx.x;
    const int lane = tid & 63;
    const int wid  = tid >> 6;
    const int base = tid * SCAN_CHUNK;

    // pass 1: per-thread sum of its chunk
    int tsum = 0;
#pragma unroll
    for (int k = 0; k < SCAN_CHUNK; ++k) {
        int i = base + k;
        tsum += (i < N_SEGMENTS) ? counts[i] : 0;
    }
    // block exclusive scan of the 1024 thread sums
    int incl = wave_incl_scan(tsum);
    if (lane == 63) wave_sums[wid] = incl;
    __syncthreads();
    if (wid == 0) {
        int ws    = (lane < 16) ? wave_sums[lane] : 0;
        int wincl = wave_incl_scan(ws);
        if (lane < 16) wave_sums[lane] = wincl - ws;
    }
    __syncthreads();
    int run = incl - tsum + wave_sums[wid];   // exclusive prefix of this thread

    // pass 2: reload and emit running exclusive prefix
#pragma unroll
    for (int k = 0; k < SCAN_CHUNK; ++k) {
        int i = base + k;
        if (i < N_SEGMENTS) {
            seg_start[i] = run;
            cursor[i]    = run;
            run += counts[i];
        }
    }
    if (tid == 1023) seg_start[N_SEGMENTS] = run;   // == N_ROWS
}

// ---------- Phase C: scatter row ids into segment-sorted order (int4) ------
__global__ void scatter_kernel(const int* __restrict__ idx,
                               int* __restrict__ cursor,
                               int* __restrict__ rowids) {
    int i = (blockIdx.x * 256 + threadIdx.x) * 4;
    if (i + 3 < N_ROWS) {
        int4 v = *(const int4*)(idx + i);
        rowids[atomicAdd(&cursor[v.x], 1)] = i;
        rowids[atomicAdd(&cursor[v.y], 1)] = i + 1;
        rowids[atomicAdd(&cursor[v.z], 1)] = i + 2;
        rowids[atomicAdd(&cursor[v.w], 1)] = i + 3;
    } else {
        for (int k = i; k < N_ROWS; ++k)
            rowids[atomicAdd(&cursor[idx[k]], 1)] = k;
    }
}

// ---------- Phase D: one wave per segment, float4 gather, no atomics -------
__global__ void __launch_bounds__(256)
reduce_kernel(const float* __restrict__ in,
              const int*   __restrict__ rowids,
              const int*   __restrict__ seg_start,
              float*       __restrict__ out) {
    const int wid  = threadIdx.x >> 6;
    const int lane = threadIdx.x & 63;
    const int seg  = blockIdx.x * 4 + wid;
    if (seg >= N_SEGMENTS) return;

    const int beg = seg_start[seg];
    const int end = seg_start[seg + 1];

    const int sub = lane >> 4;      // which of 4 rows this lane group covers
    const int c4  = lane & 15;      // float4 column within the row
    const float4* in4 = (const float4*)in;   // row = 16 float4s

    float4 acc = make_float4(0.f, 0.f, 0.f, 0.f);

    int r = beg;
    // 8 rows per iteration: two independent 4-row gathers in flight
    for (; r + 8 <= end; r += 8) {
        int row0 = rowids[r + sub];
        int row1 = rowids[r + 4 + sub];
        float4 v0 = in4[(long long)row0 * 16 + c4];
        float4 v1 = in4[(long long)row1 * 16 + c4];
        acc.x += v0.x; acc.y += v0.y; acc.z += v0.z; acc.w += v0.w;
        acc.x += v1.x; acc.y += v1.y; acc.z += v1.z; acc.w += v1.w;
    }
    for (; r + 4 <= end; r += 4) {
        int row = rowids[r + sub];
        float4 v = in4[(long long)row * 16 + c4];
        acc.x += v.x; acc.y += v.y; acc.z += v.z; acc.w += v.w;
    }
    if (r + sub < end) {            // tail: 0..3 rows
        int row = rowids[r + sub];
        float4 v = in4[(long long)row * 16 + c4];
        acc.x += v.x; acc.y += v.y; acc.z += v.z; acc.w += v.w;
    }

    // combine the 4 sub-groups (lanes differing in bits 4 and 5)
#pragma unroll
    for (int m = 16; m <= 32; m <<= 1) {
        acc.x += __shfl_xor(acc.x, m, 64);
        acc.y += __shfl_xor(acc.y, m, 64);
        acc.z += __shfl_xor(acc.z, m, 64);
        acc.w += __shfl_xor(acc.w, m, 64);
    }

    if (sub == 0) {                 // 16 lanes store 16 float4 = 256B coalesced
        ((float4*)out)[(long long)seg * 16 + c4] = acc;
    }
}

extern "C" void kernel_launch(void* const* d_in, const int* in_sizes, int n_in,
                              void* d_out, int out_size, void* d_ws, size_t ws_size,
                              hipStream_t stream) {
    const float* in  = (const float*)d_in[0];
    const int*   idx = (const int*)d_in[1];
    float*       out = (float*)d_out;

    int* counts    = (int*)d_ws;             // 50000
    int* seg_start = counts + 50048;         // 50001
    int* cursor    = seg_start + 50048;      // 50000
    int* rowids    = cursor + 50048;         // 1600000

    hipMemsetAsync(counts, 0, N_SEGMENTS * sizeof(int), stream);

    const int VEC_BLOCKS = (N_ROWS / 4 + 255) / 256;       // 1563
    hist_kernel   <<<VEC_BLOCKS, 256, 0, stream>>>(idx, counts);
    scan_kernel   <<<1, 1024, 0, stream>>>(counts, seg_start, cursor);
    scatter_kernel<<<VEC_BLOCKS, 256, 0, stream>>>(idx, cursor, rowids);

    const int SEG_BLOCKS = (N_SEGMENTS + 3) / 4;           // 12500
    reduce_kernel <<<SEG_BLOCKS, 256, 0, stream>>>(in, rowids, seg_start, out);
}

// Round 4
// 751.841 us; speedup vs baseline: 1.1224x; 1.1224x over previous
//
#include <hip/hip_runtime.h>

#define N_SEGMENTS 50000
#define N_ROWS     1600000
#define N_FEAT     64
#define SCAN_BLOCKS 196          // 196 * 256 = 50176 >= N_SEGMENTS

__device__ __forceinline__ int wave_incl_scan(int v) {
    int lane = threadIdx.x & 63;
#pragma unroll
    for (int d = 1; d < 64; d <<= 1) {
        int t = __shfl_up(v, d, 64);
        if (lane >= d) v += t;
    }
    return v;
}

// ---------- Phase A: histogram (1 elem/thread, independent atomics) --------
__global__ void hist_kernel(const int* __restrict__ idx, int* __restrict__ counts) {
    int i = blockIdx.x * 256 + threadIdx.x;
    if (i < N_ROWS) atomicAdd(&counts[idx[i]], 1);
}

// ---------- Phase B: 3-kernel multi-block exclusive scan -------------------
__global__ void scan_sums(const int* __restrict__ counts, int* __restrict__ bsums) {
    const int lane = threadIdx.x & 63, wid = threadIdx.x >> 6;
    int i = blockIdx.x * 256 + threadIdx.x;
    int v = (i < N_SEGMENTS) ? counts[i] : 0;
#pragma unroll
    for (int m = 1; m < 64; m <<= 1) v += __shfl_xor(v, m, 64);
    __shared__ int ws[4];
    if (lane == 0) ws[wid] = v;
    __syncthreads();
    if (threadIdx.x == 0) bsums[blockIdx.x] = ws[0] + ws[1] + ws[2] + ws[3];
}

__global__ void scan_mid(const int* __restrict__ bsums, int* __restrict__ boffs) {
    const int tid = threadIdx.x, lane = tid & 63, wid = tid >> 6;
    __shared__ int ws[4];
    int v = (tid < SCAN_BLOCKS) ? bsums[tid] : 0;
    int incl = wave_incl_scan(v);
    if (lane == 63) ws[wid] = incl;
    __syncthreads();
    if (wid == 0) {
        int s = (lane < 4) ? ws[lane] : 0;
        int wincl = wave_incl_scan(s);
        if (lane < 4) ws[lane] = wincl - s;
    }
    __syncthreads();
    if (tid < SCAN_BLOCKS) boffs[tid] = incl - v + ws[wid];
}

__global__ void scan_final(const int* __restrict__ counts, const int* __restrict__ boffs,
                           int* __restrict__ seg_start, int* __restrict__ cursor) {
    const int tid = threadIdx.x, lane = tid & 63, wid = tid >> 6;
    int i = blockIdx.x * 256 + tid;
    int v = (i < N_SEGMENTS) ? counts[i] : 0;
    int incl = wave_incl_scan(v);
    __shared__ int ws[4];
    if (lane == 63) ws[wid] = incl;
    __syncthreads();
    if (wid == 0) {
        int s = (lane < 4) ? ws[lane] : 0;
        int wincl = wave_incl_scan(s);
        if (lane < 4) ws[lane] = wincl - s;
    }
    __syncthreads();
    int excl = incl - v + ws[wid] + boffs[blockIdx.x];
    if (i < N_SEGMENTS) { seg_start[i] = excl; cursor[i] = excl; }
    if (blockIdx.x == 0 && tid == 0) seg_start[N_SEGMENTS] = N_ROWS;  // total is static
}

// ---------- Phase C: scatter row ids (1 elem/thread) -----------------------
__global__ void scatter_kernel(const int* __restrict__ idx,
                               int* __restrict__ cursor,
                               int* __restrict__ rowids) {
    int i = blockIdx.x * 256 + threadIdx.x;
    if (i < N_ROWS) {
        int p = atomicAdd(&cursor[idx[i]], 1);
        rowids[p] = i;
    }
}

// ---------- Phase D: one wave per segment, 16 rows in flight ---------------
__global__ void __launch_bounds__(256)
reduce_kernel(const float* __restrict__ in,
              const int*   __restrict__ rowids,
              const int*   __restrict__ seg_start,
              float*       __restrict__ out) {
    const int wid  = threadIdx.x >> 6;
    const int lane = threadIdx.x & 63;
    const int seg  = blockIdx.x * 4 + wid;
    if (seg >= N_SEGMENTS) return;

    const int beg = seg_start[seg];
    const int end = seg_start[seg + 1];

    const int sub = lane >> 4;               // 4 lane-groups -> 4 rows per load
    const int c4  = lane & 15;               // float4 column within the row
    const float4* in4 = (const float4*)in;   // row = 16 float4s

    float4 acc = make_float4(0.f, 0.f, 0.f, 0.f);

    int r = beg;
    // 16 rows per iteration: 4 independent 256B gathers per lane-group in flight
    for (; r + 16 <= end; r += 16) {
        int ra = rowids[r +      sub];
        int rb = rowids[r +  4 + sub];
        int rc = rowids[r +  8 + sub];
        int rd = rowids[r + 12 + sub];
        float4 va = in4[(long long)ra * 16 + c4];
        float4 vb = in4[(long long)rb * 16 + c4];
        float4 vc = in4[(long long)rc * 16 + c4];
        float4 vd = in4[(long long)rd * 16 + c4];
        acc.x += va.x + vb.x + vc.x + vd.x;
        acc.y += va.y + vb.y + vc.y + vd.y;
        acc.z += va.z + vb.z + vc.z + vd.z;
        acc.w += va.w + vb.w + vc.w + vd.w;
    }
    for (; r + 4 <= end; r += 4) {
        int row = rowids[r + sub];
        float4 v = in4[(long long)row * 16 + c4];
        acc.x += v.x; acc.y += v.y; acc.z += v.z; acc.w += v.w;
    }
    if (r + sub < end) {                     // tail: 0..3 rows
        int row = rowids[r + sub];
        float4 v = in4[(long long)row * 16 + c4];
        acc.x += v.x; acc.y += v.y; acc.z += v.z; acc.w += v.w;
    }

    // combine the 4 sub-groups (lanes differing in bits 4,5)
#pragma unroll
    for (int m = 16; m <= 32; m <<= 1) {
        acc.x += __shfl_xor(acc.x, m, 64);
        acc.y += __shfl_xor(acc.y, m, 64);
        acc.z += __shfl_xor(acc.z, m, 64);
        acc.w += __shfl_xor(acc.w, m, 64);
    }

    if (sub == 0) {                          // 16 lanes x float4 = 256B coalesced
        ((float4*)out)[(long long)seg * 16 + c4] = acc;
    }
}

extern "C" void kernel_launch(void* const* d_in, const int* in_sizes, int n_in,
                              void* d_out, int out_size, void* d_ws, size_t ws_size,
                              hipStream_t stream) {
    const float* in  = (const float*)d_in[0];
    const int*   idx = (const int*)d_in[1];
    float*       out = (float*)d_out;

    int* counts    = (int*)d_ws;             // 50000
    int* seg_start = counts + 50048;         // 50001
    int* cursor    = seg_start + 50048;      // 50000
    int* rowids    = cursor + 50048;         // 1600000
    int* bsums     = rowids + 1600000;       // 196
    int* boffs     = bsums + 256;            // 196

    hipMemsetAsync(counts, 0, N_SEGMENTS * sizeof(int), stream);

    const int ROW_BLOCKS = (N_ROWS + 255) / 256;           // 6250
    hist_kernel   <<<ROW_BLOCKS, 256, 0, stream>>>(idx, counts);
    scan_sums     <<<SCAN_BLOCKS, 256, 0, stream>>>(counts, bsums);
    scan_mid      <<<1, 256, 0, stream>>>(bsums, boffs);
    scan_final    <<<SCAN_BLOCKS, 256, 0, stream>>>(counts, boffs, seg_start, cursor);
    scatter_kernel<<<ROW_BLOCKS, 256, 0, stream>>>(idx, cursor, rowids);

    const int SEG_BLOCKS = (N_SEGMENTS + 3) / 4;           // 12500
    reduce_kernel <<<SEG_BLOCKS, 256, 0, stream>>>(in, rowids, seg_start, out);
}